// Round 2
// baseline (1031.993 us; speedup 1.0000x reference)
//
#include <hip/hip_runtime.h>
#include <hip/hip_bf16.h>

typedef unsigned int u32;
typedef _Float16 f16;
typedef f16 f16x2 __attribute__((ext_vector_type(2)));

#define BB 64
#define LL 128
#define TT 64
#define NN 128
#define NM (NN*NN)   // 16384

__device__ __forceinline__ float sigf(float v) {
    return 1.0f / (1.0f + __expf(-v));
}

__device__ __forceinline__ float fdot2f(f16x2 wa, f16x2 xa, float ca) {
#if defined(__HIP_DEVICE_COMPILE__) && __has_builtin(__builtin_amdgcn_fdot2)
    return __builtin_amdgcn_fdot2(wa, xa, ca, false);
#else
    return ca + (float)wa[0] * (float)xa[0] + (float)wa[1] * (float)xa[1];
#endif
}

// Kernel A: ntpT2[tp][nm] = pack_half2(sig(ntp[nm][2tp]), sig(ntp[nm][2tp+1]))
// Stored as u32 (one half2 per element). 32 * 16384 u32 = 2 MB.
__global__ __launch_bounds__(256) void sig_transpose(const float* __restrict__ ntp,
                                                     u32* __restrict__ out) {
    __shared__ float lds[64 * 65];
    const int nm0 = blockIdx.x * 64;
    const int tid = threadIdx.x;
    // load 64 rows x 64 t, coalesced; apply sigmoid
    #pragma unroll
    for (int it = 0; it < 16; ++it) {
        int idx = it * 256 + tid;
        int r = idx >> 6, c = idx & 63;
        lds[r * 65 + c] = sigf(ntp[(nm0 + r) * 64 + c]);
    }
    __syncthreads();
    // write transposed t-pair-major, coalesced over nm
    #pragma unroll
    for (int it = 0; it < 8; ++it) {
        int o = it * 256 + tid;
        int tpi = o >> 6, r = o & 63;
        f16x2 h;
        h[0] = (f16)lds[r * 65 + 2 * tpi];
        h[1] = (f16)lds[r * 65 + 2 * tpi + 1];
        out[tpi * NM + nm0 + r] = __builtin_bit_cast(u32, h);
    }
}

// Kernel B: fused recurrence. One workgroup per batch, 1024 threads.
// Thread tid owns 16 nm-slots: nm = 8*tid + 8192*k + j  (k in {0,1}, j in 0..7)
//   -> n = (tid>>4) + 64*k,  m = 8*(tid&15) + j
// cur[n] reduction = 16-lane shfl_xor tree over the (tid>>4) lane group.
__global__ __launch_bounds__(1024) void grammar_fused(
    const float* __restrict__ x_all,   // [B][L][T]
    const float* __restrict__ tp,      // [N][T] raw (sigmoid applied here)
    const u32*  __restrict__ ntpT2,    // [32][NM] half2-packed
    float* __restrict__ outp)          // [B]
{
    __shared__ float x_lds[LL * TT];        // 32 KB
    __shared__ float prevbuf[2][NN];
    __shared__ u32 x2_lds[2][32];

    const int b = blockIdx.x;
    const int tid = threadIdx.x;
    const int lane16 = tid & 15;
    const int g = tid >> 4;          // 0..63
    const int mbase = lane16 * 8;

    // stage this batch's input in LDS
    const float* xb = x_all + b * (LL * TT);
    #pragma unroll
    for (int it = 0; it < 8; ++it) {
        int idx = it * 1024 + tid;
        x_lds[idx] = xb[idx];
    }
    __syncthreads();

    // tpc init: prev[n] = sum_t sig(tp[n][t]) * x[0][t]   (NOT clipped)
    if (tid < NN) {
        float acc = 0.f;
        #pragma unroll 8
        for (int t = 0; t < TT; ++t)
            acc += sigf(tp[tid * TT + t]) * x_lds[t];
        prevbuf[0][tid] = acc;
    }
    __syncthreads();
    float out_r = 0.f;
    if (tid == 0) out_r = prevbuf[0][0];   // out0 = tpc[:,0]

    int p = 0;
    for (int i0 = 1; i0 < LL; i0 += 2) {
        const int ns = (LL - i0) >= 2 ? 2 : 1;
        // build half2-packed x for the chunk's steps
        if (tid < 64) {
            int s = tid >> 5, tpi = tid & 31;
            f16x2 h;
            if (s < ns) {
                h[0] = (f16)x_lds[(i0 + s) * TT + 2 * tpi];
                h[1] = (f16)x_lds[(i0 + s) * TT + 2 * tpi + 1];
            } else {
                h[0] = (f16)0.f; h[1] = (f16)0.f;
            }
            x2_lds[s][tpi] = __builtin_bit_cast(u32, h);
        }
        __syncthreads();

        // npc accumulators for this thread's 16 nm slots x 2 steps
        float acc[2][2][8];
        #pragma unroll
        for (int k = 0; k < 2; ++k)
            #pragma unroll
            for (int s = 0; s < 2; ++s)
                #pragma unroll
                for (int j = 0; j < 8; ++j) acc[k][s][j] = 0.f;

        #pragma unroll 2
        for (int tpi = 0; tpi < 32; ++tpi) {
            f16x2 x0 = __builtin_bit_cast(f16x2, x2_lds[0][tpi]);
            f16x2 x1 = __builtin_bit_cast(f16x2, x2_lds[1][tpi]);
            const u32* base = ntpT2 + tpi * NM + 8 * tid;
            #pragma unroll
            for (int k = 0; k < 2; ++k) {
                uint4 w0 = *reinterpret_cast<const uint4*>(base + 8192 * k);
                uint4 w1 = *reinterpret_cast<const uint4*>(base + 8192 * k + 4);
                u32 wv[8] = {w0.x, w0.y, w0.z, w0.w, w1.x, w1.y, w1.z, w1.w};
                #pragma unroll
                for (int j = 0; j < 8; ++j) {
                    f16x2 w = __builtin_bit_cast(f16x2, wv[j]);
                    acc[k][0][j] = fdot2f(w, x0, acc[k][0][j]);
                    acc[k][1][j] = fdot2f(w, x1, acc[k][1][j]);
                }
            }
        }

        // sequential recursion sub-steps within the chunk
        for (int s = 0; s < ns; ++s) {
            float4 pv0 = *reinterpret_cast<const float4*>(&prevbuf[p][mbase]);
            float4 pv1 = *reinterpret_cast<const float4*>(&prevbuf[p][mbase + 4]);
            float pvv[8] = {pv0.x, pv0.y, pv0.z, pv0.w, pv1.x, pv1.y, pv1.z, pv1.w};
            #pragma unroll
            for (int k = 0; k < 2; ++k) {
                float part = 0.f;
                #pragma unroll
                for (int j = 0; j < 8; ++j) {
                    float npc = fminf(fmaxf(acc[k][s][j], 0.f), 1.f);  // clip npc
                    part += npc * pvv[j];
                }
                part += __shfl_xor(part, 1);
                part += __shfl_xor(part, 2);
                part += __shfl_xor(part, 4);
                part += __shfl_xor(part, 8);
                if (lane16 == 0) {
                    float c = fminf(fmaxf(part, 0.f), 1.f);            // clip cur
                    prevbuf[p ^ 1][g + 64 * k] = c;
                    if (tid == 0 && k == 0) {
                        float mask = x_lds[(i0 + s) * TT + 63];
                        out_r = out_r * mask + c * (1.f - mask);
                    }
                }
            }
            p ^= 1;
            __syncthreads();
        }
    }

    if (tid == 0) outp[b] = out_r;
}

extern "C" void kernel_launch(void* const* d_in, const int* in_sizes, int n_in,
                              void* d_out, int out_size, void* d_ws, size_t ws_size,
                              hipStream_t stream) {
    const float* input_tensor = (const float*)d_in[0];   // [64][128][64]
    const float* term_prod    = (const float*)d_in[1];   // [128][64]
    const float* nonterm_prod = (const float*)d_in[2];   // [128][128][64]
    float* outp = (float*)d_out;                         // [64]
    u32* ntpT2 = (u32*)d_ws;                             // 2 MB scratch

    sig_transpose<<<256, 256, 0, stream>>>(nonterm_prod, ntpT2);
    grammar_fused<<<BB, 1024, 0, stream>>>(input_tensor, term_prod, ntpT2, outp);
}